// Round 1
// baseline (77.216 us; speedup 1.0000x reference)
//
#include <hip/hip_runtime.h>

#define IMG 100
#define OUTD 50
#define NPATCH 2500
#define NB 5
#define NGATE (NB * 8)  // per block: 4 u3 + 4 cu3

__device__ __forceinline__ float2 cmul(float2 a, float2 b) {
    return make_float2(a.x * b.x - a.y * b.y, a.x * b.y + a.y * b.x);
}
__device__ __forceinline__ float2 cadd(float2 a, float2 b) {
    return make_float2(a.x + b.x, a.y + b.y);
}

// One thread per patch. 16 complex amps in registers. Gate matrices in LDS
// (computed once per workgroup: 40 gates, one per lane of first wave-ish).
__global__ __launch_bounds__(64) void qconv_kernel(
    const float* __restrict__ img,
    const float* __restrict__ u3p,
    const float* __restrict__ cu3p,
    float* __restrict__ ez_ws)
{
    __shared__ float2 gm[NGATE][4];  // [gate][m00,m01,m10,m11]
    const int tid = threadIdx.x;

    if (tid < NGATE) {
        const int blk = tid >> 3;
        const int idx = tid & 7;
        const float* pp = (idx < 4) ? &u3p[(blk * 4 + idx) * 3]
                                    : &cu3p[(blk * 4 + (idx - 4)) * 3];
        const float th = pp[0], ph = pp[1], la = pp[2];
        float s, c, sl, cl, sp, cp, spl, cpl;
        sincosf(th * 0.5f, &s, &c);
        sincosf(la, &sl, &cl);
        sincosf(ph, &sp, &cp);
        sincosf(ph + la, &spl, &cpl);
        gm[tid][0] = make_float2(c, 0.0f);           // m00 = cos(th/2)
        gm[tid][1] = make_float2(-cl * s, -sl * s);  // m01 = -e^{i la} sin
        gm[tid][2] = make_float2(cp * s, sp * s);    // m10 =  e^{i ph} sin
        gm[tid][3] = make_float2(cpl * c, spl * c);  // m11 =  e^{i(ph+la)} cos
    }
    __syncthreads();

    const int p = blockIdx.x * blockDim.x + tid;
    if (p >= NPATCH) return;

    const int rb = p / OUTD;
    const int cb = p - rb * OUTD;
    const int i0 = 2 * rb, j0 = 2 * cb;

    // patch pixels, row-major within patch; wire w uses pixel w
    float x[4];
    x[0] = img[i0 * IMG + j0];
    x[1] = img[i0 * IMG + j0 + 1];
    x[2] = img[(i0 + 1) * IMG + j0];
    x[3] = img[(i0 + 1) * IMG + j0 + 1];

    float v[4][2];
#pragma unroll
    for (int w = 0; w < 4; ++w) {
        sincosf(x[w] * 0.5f, &v[w][1], &v[w][0]);  // RY(x)|0> = [cos, sin]
    }

    // amp index: bit (3-w) is wire w's basis bit (wire 0 = MSB)
    float2 amp[16];
#pragma unroll
    for (int i = 0; i < 16; ++i) {
        const int b0 = (i >> 3) & 1, b1 = (i >> 2) & 1, b2 = (i >> 1) & 1, b3 = i & 1;
        amp[i] = make_float2(v[0][b0] * v[1][b1] * v[2][b2] * v[3][b3], 0.0f);
    }

    const int pc[4] = {0, 1, 2, 3};
    const int pt[4] = {1, 2, 3, 0};

#pragma unroll
    for (int blk = 0; blk < NB; ++blk) {
        // single-qubit U3 on each wire
#pragma unroll
        for (int w = 0; w < 4; ++w) {
            const float2 m0 = gm[blk * 8 + w][0];
            const float2 m1 = gm[blk * 8 + w][1];
            const float2 m2 = gm[blk * 8 + w][2];
            const float2 m3 = gm[blk * 8 + w][3];
            const int sw = 1 << (3 - w);
#pragma unroll
            for (int i = 0; i < 16; ++i) {
                if ((i & sw) == 0) {
                    const float2 a0 = amp[i], a1 = amp[i + sw];
                    amp[i]      = cadd(cmul(m0, a0), cmul(m1, a1));
                    amp[i + sw] = cadd(cmul(m2, a0), cmul(m3, a1));
                }
            }
        }
        // CU3: apply u on target where control bit == 1
#pragma unroll
        for (int k = 0; k < 4; ++k) {
            const float2 m0 = gm[blk * 8 + 4 + k][0];
            const float2 m1 = gm[blk * 8 + 4 + k][1];
            const float2 m2 = gm[blk * 8 + 4 + k][2];
            const float2 m3 = gm[blk * 8 + 4 + k][3];
            const int sc = 1 << (3 - pc[k]);
            const int st = 1 << (3 - pt[k]);
#pragma unroll
            for (int i = 0; i < 16; ++i) {
                if ((i & sc) != 0 && (i & st) == 0) {
                    const float2 a0 = amp[i], a1 = amp[i + st];
                    amp[i]      = cadd(cmul(m0, a0), cmul(m1, a1));
                    amp[i + st] = cadd(cmul(m2, a0), cmul(m3, a1));
                }
            }
        }
    }

    // <Z_w> = sum_i |amp_i|^2 * (bit_w(i) ? -1 : +1)
    float ez[4] = {0.f, 0.f, 0.f, 0.f};
#pragma unroll
    for (int i = 0; i < 16; ++i) {
        const float pr = amp[i].x * amp[i].x + amp[i].y * amp[i].y;
#pragma unroll
        for (int w = 0; w < 4; ++w)
            ez[w] += ((i >> (3 - w)) & 1) ? -pr : pr;
    }
#pragma unroll
    for (int w = 0; w < 4; ++w) ez_ws[p * 4 + w] = ez[w];
}

// Single-block head: logits[q,k] = sum_j feat[q,j]*W[k,j] + b[k]; log_softmax.
// feat[q, j=cb*50+rb] = ez[p=rb*50+cb, q]
__global__ __launch_bounds__(256) void head_kernel(
    const float* __restrict__ ez_ws,
    const float* __restrict__ W,
    const float* __restrict__ b,
    float* __restrict__ out)
{
    const int tid = threadIdx.x;
    float acc[8] = {0.f, 0.f, 0.f, 0.f, 0.f, 0.f, 0.f, 0.f};

    for (int j = tid; j < NPATCH; j += 256) {
        const int cbj = j / OUTD;
        const int rbj = j - cbj * OUTD;
        const int p = rbj * OUTD + cbj;
        const float w0 = W[j];
        const float w1 = W[NPATCH + j];
#pragma unroll
        for (int q = 0; q < 4; ++q) {
            const float f = ez_ws[p * 4 + q];
            acc[q * 2 + 0] += f * w0;
            acc[q * 2 + 1] += f * w1;
        }
    }

    __shared__ float sdata[8 * 256];
#pragma unroll
    for (int i = 0; i < 8; ++i) sdata[i * 256 + tid] = acc[i];
    __syncthreads();
    for (int s = 128; s > 0; s >>= 1) {
        if (tid < s) {
#pragma unroll
            for (int i = 0; i < 8; ++i)
                sdata[i * 256 + tid] += sdata[i * 256 + tid + s];
        }
        __syncthreads();
    }
    if (tid == 0) {
        const float b0 = b[0], b1 = b[1];
#pragma unroll
        for (int q = 0; q < 4; ++q) {
            const float l0 = sdata[(q * 2 + 0) * 256] + b0;
            const float l1 = sdata[(q * 2 + 1) * 256] + b1;
            const float m = fmaxf(l0, l1);
            const float lse = m + logf(expf(l0 - m) + expf(l1 - m));
            out[q * 2 + 0] = l0 - lse;
            out[q * 2 + 1] = l1 - lse;
        }
    }
}

extern "C" void kernel_launch(void* const* d_in, const int* in_sizes, int n_in,
                              void* d_out, int out_size, void* d_ws, size_t ws_size,
                              hipStream_t stream) {
    const float* img  = (const float*)d_in[0];
    const float* u3p  = (const float*)d_in[1];
    const float* cu3p = (const float*)d_in[2];
    const float* W    = (const float*)d_in[3];
    const float* b    = (const float*)d_in[4];
    float* out   = (float*)d_out;
    float* ez_ws = (float*)d_ws;  // NPATCH*4 floats

    qconv_kernel<<<(NPATCH + 63) / 64, 64, 0, stream>>>(img, u3p, cu3p, ez_ws);
    head_kernel<<<1, 256, 0, stream>>>(ez_ws, W, b, out);
}